// Round 1
// baseline (94.479 us; speedup 1.0000x reference)
//
#include <hip/hip_runtime.h>
#include <math.h>

// Problem constants (from reference): DT=1, V_LAMBDA=1e-4, V_RIDGE=1e-4
#define LAM3  1e-4f   // V_LAMBDA / DT^6
#define RIDGE 1e-4f
#define NN    64      // N
#define NP    65      // N+1
#define ROWS  32      // batch rows per block (lanes 0..31 compute; all 64 lanes stage)

// LDS word offsets (floats). Lrec [NN][ROWS] float4 = 8192 words (32 KiB).
#define LREC_WORDS (NN * ROWS * 4)          // 8192
#define TH_OFF     LREC_WORDS               // theta stage: ROWS*65 = 2080 words
#define DXY_OFF    (TH_OFF + ROWS * NP)     // dxy stage: ROWS*129 = 4128 words (pad 129 -> odd stride)
#define OUT_OFF    DXY_OFF                  // out stage aliases dxy (dead after setup loop)
#define SMEM_WORDS (DXY_OFF + ROWS * 129)   // 14400 words = 57.6 KiB

// (D3^T D3) band values for Np=65 (third-difference smoother), boundary-truncated.
__device__ __forceinline__ float d3_diag(int f) {
    if (f == 0 || f == 64) return 1.f;
    if (f == 1 || f == 63) return 10.f;
    if (f == 2 || f == 62) return 19.f;
    return 20.f;
}
__device__ __forceinline__ float d3_off1(int f) { // [f][f-1], valid f>=1
    if (f == 1 || f == 64) return -3.f;
    if (f == 2 || f == 63) return -12.f;
    return -15.f;
}
__device__ __forceinline__ float d3_off2(int f) { // [f][f-2], valid f>=2
    if (f == 2 || f == 64) return 3.f;
    return 6.f;
}
// [f][f-3] == -1 everywhere it exists (f>=3)

__global__ __launch_bounds__(64, 1) void alpamayo_banded_solve(
    const float* __restrict__ dxy,    // [B,64,2]
    const float* __restrict__ theta,  // [B,65]
    const float* __restrict__ v0,     // [B]
    float* __restrict__ out,          // [B,65]
    int B)
{
    __shared__ __align__(16) float smem[SMEM_WORDS];

    const int tid  = threadIdx.x;
    const int base = blockIdx.x * ROWS;
    const int rows = (B - base < ROWS) ? (B - base) : ROWS;

    // ---- Phase 1: coalesced global -> LDS staging (all 64 lanes) ----
    {
        const float* thg = theta + (long)base * NP;
        const int nth = rows * NP;                       // <= 2080
        #pragma unroll
        for (int w = 0; w < (ROWS * NP + 63) / 64; ++w) {  // 33 sweeps
            const int idx = w * 64 + tid;
            if (idx < nth) smem[TH_OFF + idx] = thg[idx];  // linear: row stride 65 (odd) -> conflict-free reads
        }
        const float* dg = dxy + (long)base * (2 * NN);
        const int ndx = rows * 2 * NN;                   // <= 4096
        #pragma unroll
        for (int w = 0; w < (ROWS * 2 * NN) / 64; ++w) {   // 64 sweeps, coalesced 256B each
            const int idx = w * 64 + tid;
            if (idx < ndx) {
                const int r = idx >> 7, c = idx & 127;
                smem[DXY_OFF + r * 129 + c] = dg[idx];     // pad to odd stride 129 -> conflict-free reads
            }
        }
    }
    __syncthreads();

    const bool active = tid < rows;
    float z[NN];
    float v0b = 0.f;

    if (active) {
        v0b = v0[base + tid];
        const float* th = smem + TH_OFF  + tid * NP;     // bank (tid+f)%32 -> 2-way (free)
        const float* dx = smem + DXY_OFF + tid * 129;    // bank (tid+2f)%32 -> 2-way (free)

        // ---- Fused streaming setup: sincos + e + rhs with one-step carries ----
        float rhs[NN], e[NN];
        float cp, sp;
        __sincosf(th[0], &sp, &cp);
        float xc = dx[0], yc = dx[1];
        #pragma unroll
        for (int f = 1; f <= NN; ++f) {
            float cf, sf;
            __sincosf(th[f], &sf, &cf);
            e[f - 1] = cf * cp + sf * sp;                // cos(theta_f - theta_{f-1})
            const float xn = (f < NN) ? dx[2 * f]     : 0.f;
            const float yn = (f < NN) ? dx[2 * f + 1] : 0.f;
            rhs[f - 1] = 2.f * (cf * (xc + xn) + sf * (yc + yn));
            cp = cf; sp = sf; xc = xn; yc = yn;
        }
        // v0 corrections (couplings of reduced rows 0..2 to full index 0)
        rhs[0] -= (e[0] + LAM3 * -3.f) * v0b;
        rhs[1] -= (LAM3 *  3.f) * v0b;
        rhs[2] -= (LAM3 * -1.f) * v0b;

        // ---- Fused banded Cholesky + forward substitution (the serial chain) ----
        float4* Lr = (float4*)smem;                      // [NN][ROWS]
        float p1L1 = 0.f, p1L2 = 0.f, p2L1 = 0.f;
        float rd1 = 0.f, rd2 = 0.f, rd3 = 0.f;
        float z1 = 0.f, z2 = 0.f, z3 = 0.f;

        #pragma unroll
        for (int i = 0; i < NN; ++i) {
            const int f = i + 1;
            const float a0 = (f == NN ? 1.f : 2.f) + LAM3 * d3_diag(f) + RIDGE;
            const float a1 = e[i] + LAM3 * d3_off1(f);   // killed by rd1=0 at i=0
            const float a2 = LAM3 * d3_off2(f);          // killed by rd2=0 at i<2
            const float a3 = LAM3 * -1.f;                // killed by rd3=0 at i<3

            const float Li3 = a3 * rd3;
            const float Li2 = (a2 - Li3 * p2L1) * rd2;
            const float Li1 = (a1 - Li3 * p1L2 - Li2 * p1L1) * rd1;
            const float dg  = a0 - Li3 * Li3 - Li2 * Li2 - Li1 * Li1;
            const float rd0 = __builtin_amdgcn_rsqf(dg);

            const float zi = (rhs[i] - Li3 * z3 - Li2 * z2 - Li1 * z1) * rd0;

            Lr[i * ROWS + tid] = make_float4(Li1, Li2, Li3, rd0);
            z[i] = zi;

            p2L1 = p1L1; p1L1 = Li1; p1L2 = Li2;
            rd3 = rd2; rd2 = rd1; rd1 = rd0;
            z3 = z2; z2 = z1; z1 = zi;
        }

        // ---- Back substitution (y overwrites z in place) ----
        float r1L1 = 0.f, r1L2 = 0.f, r1L3 = 0.f;
        float r2L2 = 0.f, r2L3 = 0.f;
        float r3L3 = 0.f;
        float y1 = 0.f, y2 = 0.f, y3 = 0.f;

        #pragma unroll
        for (int i = NN - 1; i >= 0; --i) {
            const float4 rec = Lr[i * ROWS + tid];
            const float yi = (z[i] - r1L1 * y1 - r2L2 * y2 - r3L3 * y3) * rec.w;
            z[i] = yi;
            r3L3 = r2L3; r2L3 = r1L3; r2L2 = r1L2;
            r1L1 = rec.x; r1L2 = rec.y; r1L3 = rec.z;
            y3 = y2; y2 = y1; y1 = yi;
        }
    }

    // ---- Phase 3: stage result rows to LDS (aliases dxy stage; reads of it are done) ----
    __syncthreads();
    if (active) {
        float* os = smem + OUT_OFF + tid * NP;           // odd stride 65 -> conflict-free
        os[0] = v0b;
        #pragma unroll
        for (int i = 0; i < NN; ++i) os[1 + i] = z[i];
    }
    __syncthreads();

    // ---- Phase 4: coalesced LDS -> global output sweep (all 64 lanes) ----
    {
        float* og = out + (long)base * NP;
        const int nout = rows * NP;                      // <= 2080
        #pragma unroll
        for (int w = 0; w < (ROWS * NP + 63) / 64; ++w) {  // 33 sweeps, coalesced 256B each
            const int idx = w * 64 + tid;
            if (idx < nout) og[idx] = smem[OUT_OFF + idx];
        }
    }
}

extern "C" void kernel_launch(void* const* d_in, const int* in_sizes, int n_in,
                              void* d_out, int out_size, void* d_ws, size_t ws_size,
                              hipStream_t stream) {
    const float* dxy   = (const float*)d_in[0];   // [B,64,2]
    const float* theta = (const float*)d_in[1];   // [B,65]
    const float* v0    = (const float*)d_in[2];   // [B]
    float* out = (float*)d_out;                   // [B,65]
    const int B = in_sizes[2];
    const int blocks = (B + ROWS - 1) / ROWS;     // 256 blocks -> one per CU
    alpamayo_banded_solve<<<blocks, 64, 0, stream>>>(dxy, theta, v0, out, B);
}

// Round 2
// 66.406 us; speedup vs baseline: 1.4227x; 1.4227x over previous
//
#include <hip/hip_runtime.h>
#include <math.h>

// Problem constants (from reference): DT=1, V_LAMBDA=1e-4, V_RIDGE=1e-4
#define LAM3  1e-4f   // V_LAMBDA / DT^6
#define RIDGE 1e-4f
#define NN    64      // N
#define NP    65      // N+1
#define ROWS  32      // batch rows per block: lanes 0..31 compute one row each

// (D3^T D3) band values for Np=65 (third-difference smoother), boundary-truncated.
__device__ __forceinline__ float d3_diag(int f) {
    if (f == 0 || f == 64) return 1.f;
    if (f == 1 || f == 63) return 10.f;
    if (f == 2 || f == 62) return 19.f;
    return 20.f;
}
__device__ __forceinline__ float d3_off1(int f) { // [f][f-1], valid f>=1
    if (f == 1 || f == 64) return -3.f;
    if (f == 2 || f == 63) return -12.f;
    return -15.f;
}
__device__ __forceinline__ float d3_off2(int f) { // [f][f-2], valid f>=2
    if (f == 2 || f == 64) return 3.f;
    return 6.f;
}
// [f][f-3] == -1 everywhere it exists (f>=3)

__global__ __launch_bounds__(64, 1) void alpamayo_banded_solve(
    const float* __restrict__ dxy,    // [B,64,2]
    const float* __restrict__ theta,  // [B,65]
    const float* __restrict__ v0,     // [B]
    float* __restrict__ out,          // [B,65]
    int B)
{
    // LDS only for the output transpose stage (coalesced stores). 2112*4 = 8448 B.
    __shared__ float outs[ROWS * NP + 32];

    const int tid  = threadIdx.x;
    const int base = blockIdx.x * ROWS;

    if (tid < ROWS) {
        // Row-index clamp for the tail block: duplicated work, always in-bounds,
        // and crucially NO per-load guards -> all loads issue in one batch.
        int b = base + tid;
        if (b >= B) b = B - 1;

        const float*  th  = theta + (long)b * NP;
        const float4* dx4 = (const float4*)(dxy + (long)b * (2 * NN)); // row stride 512B -> 16B aligned
        const float   v0b = v0[b];

        // ---- Preload ALL inputs into registers (unconditional, one vmcnt wait) ----
        float dxf[2 * NN];
        #pragma unroll
        for (int j = 0; j < 32; ++j) {
            const float4 q = dx4[j];
            dxf[4 * j + 0] = q.x; dxf[4 * j + 1] = q.y;
            dxf[4 * j + 2] = q.z; dxf[4 * j + 3] = q.w;
        }
        float thr[NP];
        #pragma unroll
        for (int f = 0; f < NP; ++f) thr[f] = th[f];

        // ---- Setup: sincos (streamed) + off-diagonal e + rhs ----
        float e[NN], rhs[NN];
        {
            float cp, sp;
            __sincosf(thr[0], &sp, &cp);
            #pragma unroll
            for (int f = 1; f <= NN; ++f) {
                float cf, sf;
                __sincosf(thr[f], &sf, &cf);
                e[f - 1] = cf * cp + sf * sp;            // cos(theta_f - theta_{f-1})
                const float xn = (f < NN) ? dxf[2 * f]     : 0.f;
                const float yn = (f < NN) ? dxf[2 * f + 1] : 0.f;
                rhs[f - 1] = 2.f * (cf * (dxf[2 * f - 2] + xn) + sf * (dxf[2 * f - 1] + yn));
                cp = cf; sp = sf;
            }
        }
        // v0 corrections (couplings of reduced rows 0..2 to full index 0)
        rhs[0] -= (e[0] + LAM3 * -3.f) * v0b;
        rhs[1] -= (LAM3 *  3.f) * v0b;
        rhs[2] -= (LAM3 * -1.f) * v0b;

        // ---- Fused banded Cholesky + forward substitution, ALL-REGISTER ----
        float  z[NN];
        float4 Lr[NN];                       // static indices (full unroll) -> stays in VGPRs
        float p1L1 = 0.f, p1L2 = 0.f, p2L1 = 0.f;
        float rd1 = 0.f, rd2 = 0.f, rd3 = 0.f;
        float z1 = 0.f, z2 = 0.f, z3 = 0.f;

        #pragma unroll
        for (int i = 0; i < NN; ++i) {
            const int f = i + 1;
            const float a0 = (f == NN ? 1.f : 2.f) + LAM3 * d3_diag(f) + RIDGE;
            const float a1 = e[i] + LAM3 * d3_off1(f);   // killed by rd1=0 at i=0
            const float a2 = LAM3 * d3_off2(f);          // killed by rd2=0 at i<2
            const float a3 = LAM3 * -1.f;                // killed by rd3=0 at i<3

            const float Li3 = a3 * rd3;
            const float Li2 = (a2 - Li3 * p2L1) * rd2;
            const float Li1 = (a1 - Li3 * p1L2 - Li2 * p1L1) * rd1;
            const float dg  = a0 - Li3 * Li3 - Li2 * Li2 - Li1 * Li1;
            const float rd0 = __builtin_amdgcn_rsqf(dg);

            const float zi = (rhs[i] - Li3 * z3 - Li2 * z2 - Li1 * z1) * rd0;

            Lr[i] = make_float4(Li1, Li2, Li3, rd0);
            z[i] = zi;

            p2L1 = p1L1; p1L1 = Li1; p1L2 = Li2;
            rd3 = rd2; rd2 = rd1; rd1 = rd0;
            z3 = z2; z2 = z1; z1 = zi;
        }

        // ---- Back substitution, all-register (y overwrites z) ----
        float r1L1 = 0.f, r1L2 = 0.f, r1L3 = 0.f;
        float r2L2 = 0.f, r2L3 = 0.f;
        float r3L3 = 0.f;
        float y1 = 0.f, y2 = 0.f, y3 = 0.f;

        #pragma unroll
        for (int i = NN - 1; i >= 0; --i) {
            const float4 rec = Lr[i];
            const float yi = (z[i] - r1L1 * y1 - r2L2 * y2 - r3L3 * y3) * rec.w;
            z[i] = yi;
            r3L3 = r2L3; r2L3 = r1L3; r2L2 = r1L2;
            r1L1 = rec.x; r1L2 = rec.y; r1L3 = rec.z;
            y3 = y2; y2 = y1; y1 = yi;
        }

        // ---- Stage result row to LDS (stride 65 = odd -> conflict-free) ----
        float* os = outs + tid * NP;
        os[0] = v0b;
        #pragma unroll
        for (int i = 0; i < NN; ++i) os[1 + i] = z[i];
    }

    __syncthreads();

    // ---- Coalesced LDS -> global output sweep (all 64 lanes, 256B per sweep) ----
    {
        int nv = B - base;
        if (nv > ROWS) nv = ROWS;
        const int nvalid = nv * NP;                      // 2080 in the common case
        float* og = out + (long)base * NP;
        #pragma unroll
        for (int w = 0; w < (ROWS * NP + 63) / 64; ++w) {  // 33 sweeps
            const int idx = w * 64 + tid;
            if (idx < nvalid) og[idx] = outs[idx];       // predicated stores only (cheap)
        }
    }
}

extern "C" void kernel_launch(void* const* d_in, const int* in_sizes, int n_in,
                              void* d_out, int out_size, void* d_ws, size_t ws_size,
                              hipStream_t stream) {
    const float* dxy   = (const float*)d_in[0];   // [B,64,2]
    const float* theta = (const float*)d_in[1];   // [B,65]
    const float* v0    = (const float*)d_in[2];   // [B]
    float* out = (float*)d_out;                   // [B,65]
    const int B = in_sizes[2];
    const int blocks = (B + ROWS - 1) / ROWS;     // 256 blocks -> one per CU
    alpamayo_banded_solve<<<blocks, 64, 0, stream>>>(dxy, theta, v0, out, B);
}